// Round 2
// baseline (20.967 us; speedup 1.0000x reference)
//
#include <hip/hip_runtime.h>
#include <math.h>

#define DT_STEP 0.01f
#define N_FEAT 15
#define N_OUT 4
#define T_CMD 10000

// ---------------------------------------------------------------------------
// Setup: fold pro/rud into effective coefficients.
// ec[f*4 + c] = coeffs[c][f] + pro*coeffs[c][f+15] + rud*coeffs[c][f+30]
// Layout [f][c] so main kernel does float4 FMA per feature.
// ---------------------------------------------------------------------------
__global__ void boat_setup(const float* __restrict__ t,
                           const float* __restrict__ cmd,
                           const float* __restrict__ coeffs,
                           float* __restrict__ ec) {
    int i = threadIdx.x;
    if (i >= N_FEAT * N_OUT) return;
    int f = i >> 2;      // feature 0..14
    int c = i & 3;       // output channel 0..3
    int idx = (int)roundf(t[0] / DT_STEP);
    idx = idx < 0 ? 0 : (idx >= T_CMD ? T_CMD - 1 : idx);
    float pro = cmd[2 * idx];
    float rud = cmd[2 * idx + 1];
    const float* row = coeffs + c * 45;
    ec[i] = row[f] + pro * row[f + 15] + rud * row[f + 30];
}

// ---------------------------------------------------------------------------
// Main: streaming per-row polynomial evaluation.
// USE_WS=true: read precomputed ec from workspace (normal path).
// USE_WS=false: compute ec per-thread from raw inputs (ws too small fallback).
// ---------------------------------------------------------------------------
template <bool USE_WS>
__global__ void __launch_bounds__(256) boat_main(
    const float4* __restrict__ state,
    const float4* __restrict__ ec4,
    const float* __restrict__ t,
    const float* __restrict__ cmd,
    const float* __restrict__ coeffs,
    float4* __restrict__ out,
    int nrows)
{
    float4 e[N_FEAT];
    if constexpr (USE_WS) {
#pragma unroll
        for (int f = 0; f < N_FEAT; ++f) e[f] = ec4[f];
    } else {
        int idx = (int)roundf(t[0] / DT_STEP);
        idx = idx < 0 ? 0 : (idx >= T_CMD ? T_CMD - 1 : idx);
        float pro = cmd[2 * idx];
        float rud = cmd[2 * idx + 1];
#pragma unroll
        for (int f = 0; f < N_FEAT; ++f) {
            float* ef = &e[f].x;
#pragma unroll
            for (int c = 0; c < N_OUT; ++c) {
                const float* row = coeffs + c * 45;
                ef[c] = row[f] + pro * row[f + 15] + rud * row[f + 30];
            }
        }
    }

    int stride = gridDim.x * blockDim.x;
    for (int b = blockIdx.x * blockDim.x + threadIdx.x; b < nrows; b += stride) {
        float4 s = state[b];
        float u = s.x, v = s.y, r = s.z, P = s.w;
        float base[N_FEAT] = {
            1.0f, u, v, r, P,
            u * u, u * v, u * r, u * P,
            v * v, v * r, v * P,
            r * r, r * P,
            P * P
        };
        float4 acc = make_float4(0.f, 0.f, 0.f, 0.f);
#pragma unroll
        for (int f = 0; f < N_FEAT; ++f) {
            acc.x = fmaf(base[f], e[f].x, acc.x);
            acc.y = fmaf(base[f], e[f].y, acc.y);
            acc.z = fmaf(base[f], e[f].z, acc.z);
            acc.w = fmaf(base[f], e[f].w, acc.w);
        }
        out[b] = acc;
    }
}

extern "C" void kernel_launch(void* const* d_in, const int* in_sizes, int n_in,
                              void* d_out, int out_size, void* d_ws, size_t ws_size,
                              hipStream_t stream) {
    const float* t      = (const float*)d_in[0];
    const float* state  = (const float*)d_in[1];
    const float* cmd    = (const float*)d_in[2];
    const float* coeffs = (const float*)d_in[3];
    float* out = (float*)d_out;

    int nrows = in_sizes[1] / 4;   // B rows of 4 floats

    const int threads = 256;
    int blocks = 2048;
    int max_needed = (nrows + threads - 1) / threads;
    if (blocks > max_needed) blocks = max_needed;

    if (ws_size >= (size_t)(N_FEAT * N_OUT * sizeof(float))) {
        float* ec = (float*)d_ws;
        boat_setup<<<1, 64, 0, stream>>>(t, cmd, coeffs, ec);
        boat_main<true><<<blocks, threads, 0, stream>>>(
            (const float4*)state, (const float4*)ec, t, cmd, coeffs,
            (float4*)out, nrows);
    } else {
        boat_main<false><<<blocks, threads, 0, stream>>>(
            (const float4*)state, nullptr, t, cmd, coeffs,
            (float4*)out, nrows);
    }
}

// Round 3
// 17.290 us; speedup vs baseline: 1.2126x; 1.2126x over previous
//
#include <hip/hip_runtime.h>
#include <math.h>

#define DT_STEP 0.01f
#define N_FEAT 15
#define T_CMD 10000
#define ROWS_PER_THREAD 4
#define THREADS 256

__device__ __forceinline__ float4 boat_row(const float4 s, const float4* __restrict__ e) {
    float u = s.x, v = s.y, r = s.z, P = s.w;
    float base[N_FEAT];
    base[1] = u; base[2] = v; base[3] = r; base[4] = P;
    base[5] = u * u; base[6] = u * v; base[7] = u * r; base[8] = u * P;
    base[9] = v * v; base[10] = v * r; base[11] = v * P;
    base[12] = r * r; base[13] = r * P;
    base[14] = P * P;
    float4 acc = e[0];   // feature 0 is the constant 1.0
#pragma unroll
    for (int f = 1; f < N_FEAT; ++f) {
        acc.x = fmaf(base[f], e[f].x, acc.x);
        acc.y = fmaf(base[f], e[f].y, acc.y);
        acc.z = fmaf(base[f], e[f].z, acc.z);
        acc.w = fmaf(base[f], e[f].w, acc.w);
    }
    return acc;
}

__global__ void __launch_bounds__(THREADS) boat_fused(
    const float* __restrict__ t,
    const float* __restrict__ cmd,
    const float* __restrict__ coeffs,
    const float4* __restrict__ state,
    float4* __restrict__ out,
    int nrows)
{
    // ---- uniform effective-coefficient fold (scalar loads, K$-cached) ----
    int idx = (int)roundf(t[0] / DT_STEP);
    idx = idx < 0 ? 0 : (idx >= T_CMD ? T_CMD - 1 : idx);
    float pro = cmd[2 * idx];
    float rud = cmd[2 * idx + 1];
    float4 e[N_FEAT];
#pragma unroll
    for (int f = 0; f < N_FEAT; ++f) {
        float* ef = &e[f].x;
#pragma unroll
        for (int c = 0; c < 4; ++c) {
            const float* row = coeffs + c * 45;
            ef[c] = fmaf(pro, row[f + 15], fmaf(rud, row[f + 30], row[f]));
        }
    }

    // ---- streaming body: 4 rows/thread, loads hoisted ----
    int b0 = blockIdx.x * (THREADS * ROWS_PER_THREAD) + threadIdx.x;

    if (b0 + 3 * THREADS < nrows) {
        float4 s0 = state[b0];
        float4 s1 = state[b0 + THREADS];
        float4 s2 = state[b0 + 2 * THREADS];
        float4 s3 = state[b0 + 3 * THREADS];
        out[b0]               = boat_row(s0, e);
        out[b0 + THREADS]     = boat_row(s1, e);
        out[b0 + 2 * THREADS] = boat_row(s2, e);
        out[b0 + 3 * THREADS] = boat_row(s3, e);
    } else {
#pragma unroll
        for (int k = 0; k < ROWS_PER_THREAD; ++k) {
            int b = b0 + k * THREADS;
            if (b < nrows) out[b] = boat_row(state[b], e);
        }
    }
}

extern "C" void kernel_launch(void* const* d_in, const int* in_sizes, int n_in,
                              void* d_out, int out_size, void* d_ws, size_t ws_size,
                              hipStream_t stream) {
    const float* t      = (const float*)d_in[0];
    const float* state  = (const float*)d_in[1];
    const float* cmd    = (const float*)d_in[2];
    const float* coeffs = (const float*)d_in[3];
    float* out = (float*)d_out;

    int nrows = in_sizes[1] / 4;
    int blocks = (nrows + THREADS * ROWS_PER_THREAD - 1) / (THREADS * ROWS_PER_THREAD);

    boat_fused<<<blocks, THREADS, 0, stream>>>(
        t, cmd, coeffs, (const float4*)state, (float4*)out, nrows);
}